// Round 1
// baseline (600.795 us; speedup 1.0000x reference)
//
#include <hip/hip_runtime.h>

typedef short v8s __attribute__((ext_vector_type(8)));
typedef float v4f __attribute__((ext_vector_type(4)));

__device__ __forceinline__ short f2bf(float f) {
  union { float f; unsigned u; } v; v.f = f;
  unsigned r = v.u + 0x7FFFu + ((v.u >> 16) & 1u);
  return (short)(r >> 16);
}

// ---------------- elementwise cast x: fp32 -> bf16 ----------------
__global__ void cast_f32_bf16(const float* __restrict__ in, short* __restrict__ out, int n4) {
  int i = blockIdx.x * blockDim.x + threadIdx.x;
  if (i >= n4) return;
  float4 v = ((const float4*)in)[i];
  short4 o;
  o.x = f2bf(v.x); o.y = f2bf(v.y); o.z = f2bf(v.z); o.w = f2bf(v.w);
  ((short4*)out)[i] = o;
}

// ---------------- cast+transpose: fp32 [R][C] -> bf16 [C][R] ----------------
__global__ void cast_transpose_f32_bf16(const float* __restrict__ in, short* __restrict__ out,
                                        int R, int C) {
  __shared__ float tile[32][33];
  const int tx = threadIdx.x, ty = threadIdx.y;
  const int c0 = blockIdx.x * 32, r0 = blockIdx.y * 32;
#pragma unroll
  for (int i = 0; i < 4; ++i)
    tile[ty + 8 * i][tx] = in[(size_t)(r0 + ty + 8 * i) * C + c0 + tx];
  __syncthreads();
#pragma unroll
  for (int i = 0; i < 4; ++i)
    out[(size_t)(c0 + ty + 8 * i) * R + r0 + tx] = f2bf(tile[tx][ty + 8 * i]);
}

// ---------------- transpose bf16 [z][R][C] -> [z][C][R] ----------------
__global__ void transpose_bf16(const short* __restrict__ in, short* __restrict__ out,
                               int R, int C) {
  __shared__ short tile[32][33];
  const int tx = threadIdx.x, ty = threadIdx.y;
  const int c0 = blockIdx.x * 32, r0 = blockIdx.y * 32;
  const size_t zoff = (size_t)blockIdx.z * R * C;
  in += zoff; out += zoff;
#pragma unroll
  for (int i = 0; i < 4; ++i)
    tile[ty + 8 * i][tx] = in[(size_t)(r0 + ty + 8 * i) * C + c0 + tx];
  __syncthreads();
#pragma unroll
  for (int i = 0; i < 4; ++i)
    out[(size_t)(c0 + ty + 8 * i) * R + r0 + tx] = tile[tx][ty + 8 * i];
}

// ---------------- GEMM: C[M][N] = A[M][K] @ Bt[N][K]^T  (bf16 in) ----------------
// 128x128 tile, BK=32, 4 waves (2x2), each wave 64x64 = 4x4 frags of 16x16x32 MFMA.
template <int BF16_OUT>
__global__ __launch_bounds__(256) void gemm_bt(const short* __restrict__ A,
                                               const short* __restrict__ Bt,
                                               void* __restrict__ Cout,
                                               const float* __restrict__ bias,
                                               int M, int N, int K) {
  __shared__ short As[128 * 40];  // [m][k] pad 40 -> 2-way-max bank conflicts
  __shared__ short Bs[128 * 40];  // [n][k]
  const int tid = threadIdx.x;
  const int m0 = blockIdx.y * 128, n0 = blockIdx.x * 128;
  const int w = tid >> 6, lane = tid & 63, quad = lane >> 4, l16 = lane & 15;
  const int wm = (w >> 1) * 64, wn = (w & 1) * 64;
  v4f acc[4][4] = {};
  const int srow = tid >> 1, scol = (tid & 1) * 16;
  const short* Ap = A + (size_t)(m0 + srow) * K + scol;
  const short* Bp = Bt + (size_t)(n0 + srow) * K + scol;
  short* AsW = &As[srow * 40 + scol];
  short* BsW = &Bs[srow * 40 + scol];
  for (int k0 = 0; k0 < K; k0 += 32) {
    v8s a0 = *(const v8s*)Ap, a1 = *(const v8s*)(Ap + 8);
    v8s b0 = *(const v8s*)Bp, b1 = *(const v8s*)(Bp + 8);
    __syncthreads();
    *(v8s*)AsW = a0; *(v8s*)(AsW + 8) = a1;
    *(v8s*)BsW = b0; *(v8s*)(BsW + 8) = b1;
    __syncthreads();
    Ap += 32; Bp += 32;
    v8s af[4], bf[4];
#pragma unroll
    for (int i = 0; i < 4; ++i) af[i] = *(const v8s*)&As[(wm + i * 16 + l16) * 40 + quad * 8];
#pragma unroll
    for (int i = 0; i < 4; ++i) bf[i] = *(const v8s*)&Bs[(wn + i * 16 + l16) * 40 + quad * 8];
#pragma unroll
    for (int mi = 0; mi < 4; ++mi)
#pragma unroll
      for (int ni = 0; ni < 4; ++ni)
        acc[mi][ni] = __builtin_amdgcn_mfma_f32_16x16x32_bf16(af[mi], bf[ni], acc[mi][ni], 0, 0, 0);
  }
#pragma unroll
  for (int mi = 0; mi < 4; ++mi) {
#pragma unroll
    for (int ni = 0; ni < 4; ++ni) {
      const int col = n0 + wn + ni * 16 + l16;
#pragma unroll
      for (int r = 0; r < 4; ++r) {
        const int row = m0 + wm + mi * 16 + quad * 4 + r;
        if (BF16_OUT) {
          ((short*)Cout)[(size_t)row * N + col] = f2bf(acc[mi][ni][r]);
        } else {
          ((float*)Cout)[(size_t)row * N + col] = acc[mi][ni][r] + bias[col];
        }
      }
    }
  }
}

// ---------------- flash attention (causal, GQA) ----------------
// grid.x = s/64 q-tiles, grid.y = b*16 heads. 4 waves x 16 q-rows. K-tile = 32 keys.
__global__ __launch_bounds__(256) void flash_attn(const short* __restrict__ Qb,
                                                  const short* __restrict__ Kb,
                                                  const short* __restrict__ Vtb,
                                                  short* __restrict__ ctx) {
  __shared__ short Ks[32][136];   // [key][d], pad -> 2-way max
  __shared__ short Vs[128][40];   // [d][key], pad -> 2-way max
  __shared__ short Ps[4][16][32]; // per-wave P transpose buffer
  const int tid = threadIdx.x;
  const int w = tid >> 6, lane = tid & 63, quad = lane >> 4, l16 = lane & 15;
  const int q0 = blockIdx.x * 64;
  const int bh = blockIdx.y;
  const int b = bh >> 4, h = bh & 15, g = h >> 2;
  const int qrow = q0 + w * 16;
  const float scale = 0.08838834764831845f; // 1/sqrt(128)

  // Q fragments (A-layout), loaded once: rows qrow+l16, cols h*128 + kk*32 + quad*8 + j
  v8s aq[4];
  {
    const short* Qp = Qb + (size_t)(b * 2048 + qrow + l16) * 2048 + h * 128 + quad * 8;
#pragma unroll
    for (int kk = 0; kk < 4; ++kk) aq[kk] = *(const v8s*)(Qp + kk * 32);
  }
  v4f o[8] = {};
  float m_i[4] = {-1e30f, -1e30f, -1e30f, -1e30f};
  float l_i[4] = {0.f, 0.f, 0.f, 0.f};

  const int nk = (q0 + 64) >> 5;
  const int kkey = tid >> 3, kdb = (tid & 7) * 16;  // K stage: 32 keys x 128 d
  const int vd = tid >> 1, vkb = (tid & 1) * 16;    // V stage: 128 d x 32 keys
  const short* Kbase = Kb + (size_t)b * 2048 * 512 + g * 128;
  const short* Vbase = Vtb + ((size_t)b * 512 + g * 128) * 2048;

  for (int kt = 0; kt < nk; ++kt) {
    const int key0 = kt << 5;
    __syncthreads();
    {
      const short* kp = Kbase + (size_t)(key0 + kkey) * 512 + kdb;
      *(v8s*)&Ks[kkey][kdb] = *(const v8s*)kp;
      *(v8s*)&Ks[kkey][kdb + 8] = *(const v8s*)(kp + 8);
      const short* vp = Vbase + (size_t)vd * 2048 + key0 + vkb;
      *(v8s*)&Vs[vd][vkb] = *(const v8s*)vp;
      *(v8s*)&Vs[vd][vkb + 8] = *(const v8s*)(vp + 8);
    }
    __syncthreads();
    if (key0 > qrow + 15) continue;  // wave-uniform causal skip

    // S = Q @ K^T  (two 16x16 key halves)
    v4f sf0 = {0.f, 0.f, 0.f, 0.f}, sf1 = {0.f, 0.f, 0.f, 0.f};
#pragma unroll
    for (int kk = 0; kk < 4; ++kk) {
      v8s k0f = *(const v8s*)&Ks[l16][kk * 32 + quad * 8];
      v8s k1f = *(const v8s*)&Ks[16 + l16][kk * 32 + quad * 8];
      sf0 = __builtin_amdgcn_mfma_f32_16x16x32_bf16(aq[kk], k0f, sf0, 0, 0, 0);
      sf1 = __builtin_amdgcn_mfma_f32_16x16x32_bf16(aq[kk], k1f, sf1, 0, 0, 0);
    }
    float mloc[4], p0[4], p1[4], rs[4], alpha[4];
#pragma unroll
    for (int r = 0; r < 4; ++r) {
      const int row = qrow + quad * 4 + r;
      float s0 = sf0[r] * scale, s1 = sf1[r] * scale;
      if (key0 + l16 > row) s0 = -1e30f;
      if (key0 + 16 + l16 > row) s1 = -1e30f;
      sf0[r] = s0; sf1[r] = s1;
      mloc[r] = fmaxf(s0, s1);
    }
#pragma unroll
    for (int off = 1; off < 16; off <<= 1)
#pragma unroll
      for (int r = 0; r < 4; ++r) mloc[r] = fmaxf(mloc[r], __shfl_xor(mloc[r], off));
#pragma unroll
    for (int r = 0; r < 4; ++r) {
      float mn = fmaxf(m_i[r], mloc[r]);
      alpha[r] = __expf(m_i[r] - mn);
      m_i[r] = mn;
      p0[r] = __expf(sf0[r] - mn);
      p1[r] = __expf(sf1[r] - mn);
      rs[r] = p0[r] + p1[r];
    }
#pragma unroll
    for (int off = 1; off < 16; off <<= 1)
#pragma unroll
      for (int r = 0; r < 4; ++r) rs[r] += __shfl_xor(rs[r], off);
#pragma unroll
    for (int r = 0; r < 4; ++r) {
      l_i[r] = l_i[r] * alpha[r] + rs[r];
      Ps[w][quad * 4 + r][l16] = f2bf(p0[r]);
      Ps[w][quad * 4 + r][16 + l16] = f2bf(p1[r]);
    }
#pragma unroll
    for (int n = 0; n < 8; ++n)
#pragma unroll
      for (int r = 0; r < 4; ++r) o[n][r] *= alpha[r];
    __asm__ __volatile__("s_waitcnt lgkmcnt(0)" ::: "memory");
    // P (A-layout via LDS round-trip) @ V
    v8s pa = *(const v8s*)&Ps[w][l16][quad * 8];
#pragma unroll
    for (int n = 0; n < 8; ++n) {
      v8s vf = *(const v8s*)&Vs[n * 16 + l16][quad * 8];
      o[n] = __builtin_amdgcn_mfma_f32_16x16x32_bf16(pa, vf, o[n], 0, 0, 0);
    }
  }
  float inv[4];
#pragma unroll
  for (int r = 0; r < 4; ++r) inv[r] = 1.0f / l_i[r];
#pragma unroll
  for (int n = 0; n < 8; ++n)
#pragma unroll
    for (int r = 0; r < 4; ++r) {
      const int row = qrow + quad * 4 + r;
      ctx[(size_t)(b * 2048 + row) * 2048 + h * 128 + n * 16 + l16] = f2bf(o[n][r] * inv[r]);
    }
}

extern "C" void kernel_launch(void* const* d_in, const int* in_sizes, int n_in,
                              void* d_out, int out_size, void* d_ws, size_t ws_size,
                              hipStream_t stream) {
  const float* x = (const float*)d_in[0];
  const float* Wq = (const float*)d_in[1];
  const float* Wk = (const float*)d_in[2];
  const float* Wv = (const float*)d_in[3];
  const float* Wo = (const float*)d_in[4];
  const float* bo = (const float*)d_in[5];
  float* out = (float*)d_out;
  char* ws = (char*)d_ws;

  // workspace layout (bytes); ctx aliases xb (xb dead after V GEMM)
  short* xb  = (short*)(ws);                 // 16,777,216   x bf16 [4096][2048]
  short* ctx = (short*)(ws);                 // alias of xb  [4096][2048]
  short* Wqt = (short*)(ws + 16777216);      //  8,388,608   [2048 n][2048 k]
  short* Wkt = (short*)(ws + 25165824);      //  2,097,152   [512 n][2048 k]
  short* Wvt = (short*)(ws + 27262976);      //  2,097,152
  short* Wot = (short*)(ws + 29360128);      //  8,388,608
  short* Qb  = (short*)(ws + 37748736);      // 16,777,216   [4096][2048]
  short* Kb  = (short*)(ws + 54525952);      //  4,194,304   [4096][512]
  short* Vb  = (short*)(ws + 58720256);      //  4,194,304
  short* Vtb = (short*)(ws + 62914560);      //  4,194,304   [b][512][2048]
  // total: 67,108,864 bytes

  dim3 tb(32, 8);
  cast_f32_bf16<<<8192, 256, 0, stream>>>(x, xb, 2097152);
  cast_transpose_f32_bf16<<<dim3(64, 64), tb, 0, stream>>>(Wq, Wqt, 2048, 2048);
  cast_transpose_f32_bf16<<<dim3(16, 64), tb, 0, stream>>>(Wk, Wkt, 2048, 512);
  cast_transpose_f32_bf16<<<dim3(16, 64), tb, 0, stream>>>(Wv, Wvt, 2048, 512);
  cast_transpose_f32_bf16<<<dim3(64, 64), tb, 0, stream>>>(Wo, Wot, 2048, 2048);

  gemm_bt<1><<<dim3(16, 32), 256, 0, stream>>>(xb, Wqt, (void*)Qb, nullptr, 4096, 2048, 2048);
  gemm_bt<1><<<dim3(4, 32), 256, 0, stream>>>(xb, Wkt, (void*)Kb, nullptr, 4096, 512, 2048);
  gemm_bt<1><<<dim3(4, 32), 256, 0, stream>>>(xb, Wvt, (void*)Vb, nullptr, 4096, 512, 2048);

  transpose_bf16<<<dim3(16, 64, 2), tb, 0, stream>>>(Vb, Vtb, 2048, 512);

  flash_attn<<<dim3(32, 32), 256, 0, stream>>>(Qb, Kb, Vtb, ctx);

  gemm_bt<0><<<dim3(16, 32), 256, 0, stream>>>(ctx, Wot, (void*)out, bo, 4096, 2048, 2048);
}

// Round 2
// 346.777 us; speedup vs baseline: 1.7325x; 1.7325x over previous
//
#include <hip/hip_runtime.h>

typedef short v8s __attribute__((ext_vector_type(8)));
typedef float v4f __attribute__((ext_vector_type(4)));

__device__ __forceinline__ short f2bf(float f) {
  union { float f; unsigned u; } v; v.f = f;
  unsigned r = v.u + 0x7FFFu + ((v.u >> 16) & 1u);
  return (short)(r >> 16);
}

// async global->LDS, 16B per lane; LDS dst = wave-uniform base + lane*16
__device__ __forceinline__ void gll16(const short* g, short* l) {
  __builtin_amdgcn_global_load_lds(
      (const __attribute__((address_space(1))) void*)g,
      (__attribute__((address_space(3))) void*)l, 16, 0, 0);
}

// ---------------- elementwise cast x: fp32 -> bf16 ----------------
__global__ void cast_f32_bf16(const float* __restrict__ in, short* __restrict__ out, int n4) {
  int i = blockIdx.x * blockDim.x + threadIdx.x;
  if (i >= n4) return;
  float4 v = ((const float4*)in)[i];
  short4 o;
  o.x = f2bf(v.x); o.y = f2bf(v.y); o.z = f2bf(v.z); o.w = f2bf(v.w);
  ((short4*)out)[i] = o;
}

// ---------------- cast+transpose: fp32 [R][C] -> bf16 [C][R] ----------------
__global__ void cast_transpose_f32_bf16(const float* __restrict__ in, short* __restrict__ out,
                                        int R, int C) {
  __shared__ float tile[32][33];
  const int tx = threadIdx.x, ty = threadIdx.y;
  const int c0 = blockIdx.x * 32, r0 = blockIdx.y * 32;
#pragma unroll
  for (int i = 0; i < 4; ++i)
    tile[ty + 8 * i][tx] = in[(size_t)(r0 + ty + 8 * i) * C + c0 + tx];
  __syncthreads();
#pragma unroll
  for (int i = 0; i < 4; ++i)
    out[(size_t)(c0 + ty + 8 * i) * R + r0 + tx] = f2bf(tile[tx][ty + 8 * i]);
}

// ---------------- V transpose out of packed QKV ----------------
// QKV [b*2048 rows][3072], V at col 2560 + (0..511). out Vtb [b][512][2048]
__global__ void transpose_v(const short* __restrict__ qkv, short* __restrict__ out) {
  __shared__ short tile[32][33];
  const int tx = threadIdx.x, ty = threadIdx.y;
  const int c0 = blockIdx.x * 32, r0 = blockIdx.y * 32;
  const int z = blockIdx.z;
#pragma unroll
  for (int i = 0; i < 4; ++i)
    tile[ty + 8 * i][tx] = qkv[(size_t)(z * 2048 + r0 + ty + 8 * i) * 3072 + 2560 + c0 + tx];
  __syncthreads();
#pragma unroll
  for (int i = 0; i < 4; ++i)
    out[(size_t)z * 512 * 2048 + (size_t)(c0 + ty + 8 * i) * 2048 + r0 + tx] = tile[tx][ty + 8 * i];
}

// ---------------- GEMM: C[M][N] = A[M][K] @ Bt[N][K]^T  (bf16 in) ----------------
// m97 structure: 128x128 tile, BK=32, 4 waves, global_load_lds width-16 staging,
// unpadded LDS (GLL dst must be lane-contiguous).
template <int BF16_OUT>
__global__ __launch_bounds__(256) void gemm_bt(const short* __restrict__ A,
                                               const short* __restrict__ Bt,
                                               void* __restrict__ Cout,
                                               const float* __restrict__ bias,
                                               int M, int N, int K) {
  __shared__ short As[128 * 32];
  __shared__ short Bs[128 * 32];
  const int tid = threadIdx.x;
  const int m0 = blockIdx.y * 128, n0 = blockIdx.x * 128;
  const int w = tid >> 6, lane = tid & 63, quad = lane >> 4, l16 = lane & 15;
  const int wm = (w >> 1) * 64, wn = (w & 1) * 64;
  v4f acc[4][4] = {};
  // staging: wave w covers rows w*32..w*32+31 of both tiles; 2 insts each for A,B
  const int srow = lane >> 2, scol = (lane & 3) * 8;  // 16 rows x 32 cols per inst
  const short* Ap = A + (size_t)(m0 + w * 32 + srow) * K + scol;
  const short* Bp = Bt + (size_t)(n0 + w * 32 + srow) * K + scol;
  short* AsW = &As[(w * 32) * 32 + lane * 8];
  short* BsW = &Bs[(w * 32) * 32 + lane * 8];
  const size_t rstep = (size_t)16 * K;
  for (int k0 = 0; k0 < K; k0 += 32) {
    __syncthreads();
    gll16(Ap, AsW);
    gll16(Ap + rstep, AsW + 16 * 32);
    gll16(Bp, BsW);
    gll16(Bp + rstep, BsW + 16 * 32);
    __syncthreads();
    Ap += 32; Bp += 32;
    v8s af[4], bf[4];
#pragma unroll
    for (int i = 0; i < 4; ++i) af[i] = *(const v8s*)&As[(wm + i * 16 + l16) * 32 + quad * 8];
#pragma unroll
    for (int i = 0; i < 4; ++i) bf[i] = *(const v8s*)&Bs[(wn + i * 16 + l16) * 32 + quad * 8];
#pragma unroll
    for (int mi = 0; mi < 4; ++mi)
#pragma unroll
      for (int ni = 0; ni < 4; ++ni)
        acc[mi][ni] = __builtin_amdgcn_mfma_f32_16x16x32_bf16(af[mi], bf[ni], acc[mi][ni], 0, 0, 0);
  }
#pragma unroll
  for (int mi = 0; mi < 4; ++mi) {
#pragma unroll
    for (int ni = 0; ni < 4; ++ni) {
      const int col = n0 + wn + ni * 16 + l16;
#pragma unroll
      for (int r = 0; r < 4; ++r) {
        const int row = m0 + wm + mi * 16 + quad * 4 + r;
        if (BF16_OUT) {
          ((short*)Cout)[(size_t)row * N + col] = f2bf(acc[mi][ni][r]);
        } else {
          ((float*)Cout)[(size_t)row * N + col] = acc[mi][ni][r] + bias[col];
        }
      }
    }
  }
}

// ---------------- flash attention v2 (causal, GQA) ----------------
// grid: (16 q-tile pairs, b*16 heads). Block = 4 waves x 16 q-rows = 64 rows.
// Pairing: block x handles q-tiles x and 31-x -> constant work per block.
// K-tile = 64 keys (halves softmax/barrier cost per key vs 32).
__global__ __launch_bounds__(256) void flash_attn2(const short* __restrict__ QKV,
                                                   const short* __restrict__ Vtb,
                                                   short* __restrict__ ctx) {
  __shared__ short Ks[64][136];   // [key][d]   pad -> 2-way max
  __shared__ short Vs[128][72];   // [d][key]   pad -> 2-way max
  __shared__ short Ps[4][16][72]; // per-wave P transpose, pad -> 2-way max
  const int tid = threadIdx.x;
  const int w = tid >> 6, lane = tid & 63, quad = lane >> 4, l16 = lane & 15;
  const int bh = blockIdx.y;
  const int b = bh >> 4, h = bh & 15, g = h >> 2;
  const float scale = 0.08838834764831845f; // 1/sqrt(128)

  // staging index split
  const int krow = tid >> 2, kc = (tid & 3) * 32;  // K: 64 rows x 128 cols
  const int vrow = tid >> 1, vc = (tid & 1) * 32;  // V: 128 rows x 64 cols
  const short* Kbase = QKV + 2048 + g * 128;                 // + row*3072
  const short* Vbase = Vtb + ((size_t)b * 512 + g * 128) * 2048;

#pragma unroll 1
  for (int half = 0; half < 2; ++half) {
    const int qt = half ? (31 - blockIdx.x) : blockIdx.x;
    const int q0 = qt * 64;
    const int qrow = q0 + w * 16;

    v8s aq[4];
    {
      const short* Qp = QKV + (size_t)(b * 2048 + qrow + l16) * 3072 + h * 128 + quad * 8;
#pragma unroll
      for (int kk = 0; kk < 4; ++kk) aq[kk] = *(const v8s*)(Qp + kk * 32);
    }
    v4f o[8] = {};
    float m_i[4] = {-1e30f, -1e30f, -1e30f, -1e30f};
    float l_i[4] = {0.f, 0.f, 0.f, 0.f};

    const int nk = qt + 1;
#pragma unroll 1
    for (int kt = 0; kt < nk; ++kt) {
      const int key0 = kt << 6;
      __syncthreads();
      {
        const short* kp = Kbase + (size_t)(b * 2048 + key0 + krow) * 3072 + kc;
        const short* vp = Vbase + (size_t)vrow * 2048 + key0 + vc;
#pragma unroll
        for (int j = 0; j < 4; ++j) {
          *(v8s*)&Ks[krow][kc + j * 8] = *(const v8s*)(kp + j * 8);
          *(v8s*)&Vs[vrow][vc + j * 8] = *(const v8s*)(vp + j * 8);
        }
      }
      __syncthreads();

      // S = Q @ K^T : 4 key-frags of 16
      v4f sf[4] = {};
#pragma unroll
      for (int kf = 0; kf < 4; ++kf)
#pragma unroll
        for (int kk = 0; kk < 4; ++kk) {
          v8s kfr = *(const v8s*)&Ks[kf * 16 + l16][kk * 32 + quad * 8];
          sf[kf] = __builtin_amdgcn_mfma_f32_16x16x32_bf16(aq[kk], kfr, sf[kf], 0, 0, 0);
        }

      float mloc[4], p[4][4], rs[4], alpha[4];
      const bool diag = (key0 + 63 > qrow);  // masking needed only on diagonal tile
#pragma unroll
      for (int r = 0; r < 4; ++r) {
        const int row = qrow + quad * 4 + r;
#pragma unroll
        for (int kf = 0; kf < 4; ++kf) {
          float s = sf[kf][r] * scale;
          if (diag && (key0 + kf * 16 + l16 > row)) s = -1e30f;
          sf[kf][r] = s;
        }
        mloc[r] = fmaxf(fmaxf(sf[0][r], sf[1][r]), fmaxf(sf[2][r], sf[3][r]));
      }
#pragma unroll
      for (int off = 1; off < 16; off <<= 1)
#pragma unroll
        for (int r = 0; r < 4; ++r) mloc[r] = fmaxf(mloc[r], __shfl_xor(mloc[r], off));
#pragma unroll
      for (int r = 0; r < 4; ++r) {
        const float mn = fmaxf(m_i[r], mloc[r]);
        alpha[r] = __expf(m_i[r] - mn);
        m_i[r] = mn;
        rs[r] = 0.f;
#pragma unroll
        for (int kf = 0; kf < 4; ++kf) {
          p[kf][r] = __expf(sf[kf][r] - mn);
          rs[r] += p[kf][r];
        }
      }
#pragma unroll
      for (int off = 1; off < 16; off <<= 1)
#pragma unroll
        for (int r = 0; r < 4; ++r) rs[r] += __shfl_xor(rs[r], off);
#pragma unroll
      for (int r = 0; r < 4; ++r) {
        l_i[r] = l_i[r] * alpha[r] + rs[r];
#pragma unroll
        for (int kf = 0; kf < 4; ++kf)
          Ps[w][quad * 4 + r][kf * 16 + l16] = f2bf(p[kf][r]);
      }
#pragma unroll
      for (int n = 0; n < 8; ++n)
#pragma unroll
        for (int r = 0; r < 4; ++r) o[n][r] *= alpha[r];
      __asm__ __volatile__("s_waitcnt lgkmcnt(0)" ::: "memory");
      // P @ V : P in A-layout via LDS round-trip, 2 k-chunks of 32 keys
      v8s pa0 = *(const v8s*)&Ps[w][l16][quad * 8];
      v8s pa1 = *(const v8s*)&Ps[w][l16][32 + quad * 8];
#pragma unroll
      for (int n = 0; n < 8; ++n) {
        v8s vf0 = *(const v8s*)&Vs[n * 16 + l16][quad * 8];
        v8s vf1 = *(const v8s*)&Vs[n * 16 + l16][32 + quad * 8];
        o[n] = __builtin_amdgcn_mfma_f32_16x16x32_bf16(pa0, vf0, o[n], 0, 0, 0);
        o[n] = __builtin_amdgcn_mfma_f32_16x16x32_bf16(pa1, vf1, o[n], 0, 0, 0);
      }
    }
    float inv[4];
#pragma unroll
    for (int r = 0; r < 4; ++r) inv[r] = 1.0f / l_i[r];
#pragma unroll
    for (int n = 0; n < 8; ++n)
#pragma unroll
      for (int r = 0; r < 4; ++r) {
        const int row = qrow + quad * 4 + r;
        ctx[(size_t)(b * 2048 + row) * 2048 + h * 128 + n * 16 + l16] = f2bf(o[n][r] * inv[r]);
      }
  }
}

extern "C" void kernel_launch(void* const* d_in, const int* in_sizes, int n_in,
                              void* d_out, int out_size, void* d_ws, size_t ws_size,
                              hipStream_t stream) {
  const float* x = (const float*)d_in[0];
  const float* Wq = (const float*)d_in[1];
  const float* Wk = (const float*)d_in[2];
  const float* Wv = (const float*)d_in[3];
  const float* Wo = (const float*)d_in[4];
  const float* bo = (const float*)d_in[5];
  float* out = (float*)d_out;
  char* ws = (char*)d_ws;

  // workspace layout (bytes), total exactly 64 MiB; ctx aliases xb
  short* xb    = (short*)(ws);             // 16,777,216  x bf16 [4096][2048]
  short* ctx   = (short*)(ws);             // alias       [4096][2048]
  short* Wqkvt = (short*)(ws + 16777216);  // 12,582,912  [3072 n][2048 k] packed Q|K|V
  short* Wot   = (short*)(ws + 29360128);  //  8,388,608  [2048 n][2048 k]
  short* QKV   = (short*)(ws + 37748736);  // 25,165,824  [4096][3072]
  short* Vtb   = (short*)(ws + 62914560);  //  4,194,304  [b][512][2048]

  dim3 tb(32, 8);
  cast_f32_bf16<<<8192, 256, 0, stream>>>(x, xb, 2097152);
  cast_transpose_f32_bf16<<<dim3(64, 64), tb, 0, stream>>>(Wq, Wqkvt, 2048, 2048);
  cast_transpose_f32_bf16<<<dim3(16, 64), tb, 0, stream>>>(Wk, Wqkvt + (size_t)2048 * 2048, 2048, 512);
  cast_transpose_f32_bf16<<<dim3(16, 64), tb, 0, stream>>>(Wv, Wqkvt + (size_t)2560 * 2048, 2048, 512);
  cast_transpose_f32_bf16<<<dim3(64, 64), tb, 0, stream>>>(Wo, Wot, 2048, 2048);

  // fused QKV projection: [4096 x 2048] @ [2048 x 3072]
  gemm_bt<1><<<dim3(24, 32), 256, 0, stream>>>(xb, Wqkvt, (void*)QKV, nullptr, 4096, 3072, 2048);

  transpose_v<<<dim3(16, 64, 2), tb, 0, stream>>>(QKV, Vtb);

  flash_attn2<<<dim3(16, 32), 256, 0, stream>>>(QKV, Vtb, ctx);

  gemm_bt<0><<<dim3(16, 32), 256, 0, stream>>>(ctx, Wot, (void*)out, bo, 4096, 2048, 2048);
}